// Round 11
// baseline (192.230 us; speedup 1.0000x reference)
//
#include <hip/hip_runtime.h>

typedef __attribute__((ext_vector_type(8))) __bf16 bf16x8;
typedef __attribute__((ext_vector_type(4))) __bf16 bf16x4;
typedef __attribute__((ext_vector_type(4))) float  f32x4;

static constexpr int TSEQ    = 2048;
static constexpr int DMODEL  = 1024;
static constexpr int HD      = 64;
static constexpr int VSTRIDE = 2080;   // V^T row stride (breaks 4KB L2-channel aliasing)
static constexpr int LSTR    = 72;     // attn LDS row stride

#define AS1 __attribute__((address_space(1)))
#define AS3 __attribute__((address_space(3)))

__device__ __forceinline__ float fast_exp2(float x) {
  return __builtin_amdgcn_exp2f(x);    // raw v_exp_f32
}

// ---------------- fused preprocessing: convert x + transpose weights ----------------
__global__ __launch_bounds__(256) void k_prep(const float* __restrict__ x,
    const float* __restrict__ w0, const float* __restrict__ w1,
    const float* __restrict__ w2, const float* __restrict__ w3,
    __bf16* __restrict__ xbf, __bf16* __restrict__ wt_all) {
  __shared__ float tile[32][33];
  const int blk = blockIdx.x;
  const int tid = threadIdx.x;
  if (blk < 4096) {
    size_t i = ((size_t)blk * 256 + tid) * 4;
    float4 v = *(const float4*)(x + i);
    bf16x4 o = { (__bf16)v.x, (__bf16)v.y, (__bf16)v.z, (__bf16)v.w };
    *(bf16x4*)(xbf + i) = o;
    return;
  }
  const int tz = blk - 4096;
  const int wi = tz >> 10;
  const int tl = tz & 1023;
  const int n0 = (tl & 31) * 32, k0 = (tl >> 5) * 32;
  const float* w = wi == 0 ? w0 : wi == 1 ? w1 : wi == 2 ? w2 : w3;
  __bf16* out = wt_all + (size_t)wi * DMODEL * DMODEL;
  const int tx = tid & 31, ty0 = (tid >> 5) * 4;
#pragma unroll
  for (int j = 0; j < 4; j++)
    tile[ty0 + j][tx] = w[(size_t)(k0 + ty0 + j) * DMODEL + n0 + tx];
  __syncthreads();
#pragma unroll
  for (int j = 0; j < 4; j++)
    out[(size_t)(n0 + ty0 + j) * DMODEL + k0 + tx] = (__bf16)tile[tx][ty0 + j];
}

// ---------------- m97-style GEMM mainloop: global_load_lds width-16, BK=32 ----------------
__device__ __forceinline__ void gemm_mainloop(const __bf16* __restrict__ A,
                                              const __bf16* __restrict__ Bt,
                                              int bm, int bn,
                                              __bf16* At, __bf16* Bl,
                                              f32x4 acc[4][4]) {
  const int tid  = threadIdx.x;
  const int lane = tid & 63;
  const int l15  = lane & 15, quad = lane >> 4;
  const int wv   = tid >> 6;
  const int wm   = (wv >> 1) * 64, wn = (wv & 1) * 64;
  const int s0   = wv * 2;
  const int srow = lane >> 2;
  const int scol = (lane & 3) << 3;
  for (int k0 = 0; k0 < 1024; k0 += 32) {
    __syncthreads();
#pragma unroll
    for (int ss = 0; ss < 2; ss++) {
      const int s   = s0 + ss;
      const int row = s * 16 + srow;
      const __bf16* ga = A  + (size_t)(bm + row) * 1024 + k0 + scol;
      const __bf16* gb = Bt + (size_t)(bn + row) * 1024 + k0 + scol;
      __builtin_amdgcn_global_load_lds((const AS1 void*)ga,
                                       (AS3 void*)(At + s * 512), 16, 0, 0);
      __builtin_amdgcn_global_load_lds((const AS1 void*)gb,
                                       (AS3 void*)(Bl + s * 512), 16, 0, 0);
    }
    __syncthreads();
    bf16x8 af[4], bfr[4];
#pragma unroll
    for (int mt = 0; mt < 4; mt++)
      af[mt] = *(const bf16x8*)(At + (wm + mt * 16 + l15) * 32 + quad * 8);
#pragma unroll
    for (int nt = 0; nt < 4; nt++)
      bfr[nt] = *(const bf16x8*)(Bl + (wn + nt * 16 + l15) * 32 + quad * 8);
#pragma unroll
    for (int mt = 0; mt < 4; mt++)
#pragma unroll
      for (int nt = 0; nt < 4; nt++)
        acc[mt][nt] = __builtin_amdgcn_mfma_f32_16x16x32_bf16(
            af[mt], bfr[nt], acc[mt][nt], 0, 0, 0);
  }
}

// ---------------- QKV projection (Q pre-scaled by log2e/8 for exp2 softmax) ----------------
__global__ __launch_bounds__(256) void k_gemm_qkv(const __bf16* __restrict__ xbf,
    const __bf16* __restrict__ wt_all, __bf16* __restrict__ qws,
    __bf16* __restrict__ kws, __bf16* __restrict__ vtws) {
  __shared__ __bf16 At[128 * 32];
  __shared__ __bf16 Bl[128 * 32];
  const int which = blockIdx.z;
  const __bf16* wt = wt_all + (size_t)which * DMODEL * DMODEL;
  const int bm = blockIdx.y * 128, bn = blockIdx.x * 128;
  f32x4 acc[4][4];
  const f32x4 z = {0.f, 0.f, 0.f, 0.f};
#pragma unroll
  for (int mt = 0; mt < 4; mt++)
#pragma unroll
    for (int nt = 0; nt < 4; nt++) acc[mt][nt] = z;
  gemm_mainloop(xbf, wt, bm, bn, At, Bl, acc);
  const int lane = threadIdx.x & 63;
  const int l15 = lane & 15, quad = lane >> 4;
  const int wv = threadIdx.x >> 6;
  const int wm = (wv >> 1) * 64, wn = (wv & 1) * 64;
#pragma unroll
  for (int mt = 0; mt < 4; mt++)
#pragma unroll
    for (int nt = 0; nt < 4; nt++)
#pragma unroll
      for (int r = 0; r < 4; r++) {
        int m = bm + wm + mt * 16 + quad * 4 + r;
        int n = bn + wn + nt * 16 + l15;
        int b = m >> 11, t = m & 2047;
        int h = n >> 6,  d = n & 63;
        int bh = b * 16 + h;
        float av = acc[mt][nt][r];
        // 0.18033688 = log2(e)/8: folds the 1/sqrt(64) scale AND ln->log2 for exp2 softmax
        if (which == 0)      qws[((size_t)bh * TSEQ + t) * HD + d] = (__bf16)(av * 0.18033688f);
        else if (which == 1) kws[((size_t)bh * TSEQ + t) * HD + d] = (__bf16)av;
        else                 vtws[((size_t)bh * HD + d) * VSTRIDE + t] = (__bf16)av;
      }
}

// ---------------- flash attention: dual-half per staged K/V tile ----------------
// Block owns q-blocks (qb0, 31-qb0), processes BOTH against each staged tile:
// K/V frag regs shared by both halves' MFMAs -> frag reads halved on dual tiles,
// staging windows per CU 66 -> 49 (qidx pairing balances), 32 MFMA/window.
// bh = blk&31 keeps the round-robin XCD mapping (bh%8) -> L2-resident K/V.
__global__ __launch_bounds__(256) void k_attn(const __bf16* __restrict__ qws,
    const __bf16* __restrict__ kws, const __bf16* __restrict__ vtws,
    __bf16* __restrict__ ctx) {
  const int blk  = blockIdx.x;
  const int bh   = blk & 31;
  const int qidx = blk >> 5;
  const int qb0  = qidx < 8 ? qidx : 23 - qidx;   // 0..15
  const int qb1  = 31 - qb0;                      // 16..31
  const int tid = threadIdx.x;
  const int lane = tid & 63, wv = tid >> 6;
  const int l15 = lane & 15, quad = lane >> 4;
  const __bf16* qp = qws  + (size_t)bh * TSEQ * HD;
  const __bf16* kp = kws  + (size_t)bh * TSEQ * HD;
  const __bf16* vp = vtws + (size_t)bh * HD * VSTRIDE;
  const int b = bh >> 4, h = bh & 15;

  __shared__ __bf16 kbuf[2][64 * LSTR];
  __shared__ __bf16 vbuf[2][64 * LSTR];
  __shared__ __bf16 pldsa[4][16 * LSTR];
  __shared__ __bf16 pldsb[4][16 * LSTR];

  const f32x4 z = {0.f, 0.f, 0.f, 0.f};
  const int sr = tid >> 3, sc = (tid & 7) * 8;

  const int qr0a = qb0 * 64 + wv * 16;
  const int qr0b = qb1 * 64 + wv * 16;
  bf16x8 aqa[2], aqb[2];
#pragma unroll
  for (int kb = 0; kb < 2; kb++) {
    aqa[kb] = *(const bf16x8*)(qp + (size_t)(qr0a + l15) * HD + kb * 32 + quad * 8);
    aqb[kb] = *(const bf16x8*)(qp + (size_t)(qr0b + l15) * HD + kb * 32 + quad * 8);
  }

  bf16x8 kreg[2], vreg[2];
  auto load_tile = [&](int s) {
    const int kt = s * 64;
    kreg[0] = *(const bf16x8*)(kp + (size_t)(kt + sr) * HD + sc);
    kreg[1] = *(const bf16x8*)(kp + (size_t)(kt + sr + 32) * HD + sc);
    vreg[0] = *(const bf16x8*)(vp + (size_t)sr * VSTRIDE + kt + sc);
    vreg[1] = *(const bf16x8*)(vp + (size_t)(sr + 32) * VSTRIDE + kt + sc);
  };
  auto store_tile = [&](int buf) {
    *(bf16x8*)(kbuf[buf] + sr * LSTR + sc)        = kreg[0];
    *(bf16x8*)(kbuf[buf] + (sr + 32) * LSTR + sc) = kreg[1];
    *(bf16x8*)(vbuf[buf] + sr * LSTR + sc)        = vreg[0];
    *(bf16x8*)(vbuf[buf] + (sr + 32) * LSTR + sc) = vreg[1];
  };

  float lpa[4] = {0.f, 0.f, 0.f, 0.f};
  float lpb[4] = {0.f, 0.f, 0.f, 0.f};
  f32x4 acca[4], accb[4];
#pragma unroll
  for (int dt = 0; dt < 4; dt++) { acca[dt] = z; accb[dt] = z; }

  auto finalize = [&](float* lp, f32x4* acc, int qr0) {
#pragma unroll
    for (int r = 0; r < 4; r++) {
      float l = lp[r];
      l += __shfl_xor(l, 1, 64);
      l += __shfl_xor(l, 2, 64);
      l += __shfl_xor(l, 4, 64);
      l += __shfl_xor(l, 8, 64);
      float linv = 1.f / l;
      const int qrow = qr0 + quad * 4 + r;
#pragma unroll
      for (int dt = 0; dt < 4; dt++)
        ctx[((size_t)(b * TSEQ + qrow)) * DMODEL + h * 64 + dt * 16 + l15] =
            (__bf16)(acc[dt][r] * linv);
    }
  };

  // prologue
  load_tile(0);
  store_tile(0);
  __syncthreads();

  for (int s = 0; s <= qb1; s++) {
    const int cur = s & 1;
    const bool dual = (s <= qb0);

    if (s + 1 <= qb1) load_tile(s + 1);

    const __bf16* kb_ = kbuf[cur];
    const __bf16* vb_ = vbuf[cur];
    f32x4 sa[4], sb[4];
#pragma unroll
    for (int nt = 0; nt < 4; nt++) { sb[nt] = z; sa[nt] = z; }

    if (dual) {
#pragma unroll
      for (int nt = 0; nt < 4; nt++)
#pragma unroll
        for (int kb = 0; kb < 2; kb++) {
          bf16x8 bk = *(const bf16x8*)(kb_ + (nt * 16 + l15) * LSTR + kb * 32 + quad * 8);
          sb[nt] = __builtin_amdgcn_mfma_f32_16x16x32_bf16(aqb[kb], bk, sb[nt], 0, 0, 0);
          sa[nt] = __builtin_amdgcn_mfma_f32_16x16x32_bf16(aqa[kb], bk, sa[nt], 0, 0, 0);
        }
    } else {
#pragma unroll
      for (int nt = 0; nt < 4; nt++)
#pragma unroll
        for (int kb = 0; kb < 2; kb++) {
          bf16x8 bk = *(const bf16x8*)(kb_ + (nt * 16 + l15) * LSTR + kb * 32 + quad * 8);
          sb[nt] = __builtin_amdgcn_mfma_f32_16x16x32_bf16(aqb[kb], bk, sb[nt], 0, 0, 0);
        }
    }

    // softmax half b (masked only at its frontier s==qb1)
    if (s == qb1) {
#pragma unroll
      for (int r = 0; r < 4; r++) {
        const int qloc = wv * 16 + quad * 4 + r;
#pragma unroll
        for (int nt = 0; nt < 4; nt++) {
          int kloc = nt * 16 + l15;
          float p = (kloc <= qloc) ? fast_exp2(sb[nt][r]) : 0.f;
          lpb[r] += p;
          pldsb[wv][(quad * 4 + r) * LSTR + nt * 16 + l15] = (__bf16)p;
        }
      }
    } else {
#pragma unroll
      for (int r = 0; r < 4; r++)
#pragma unroll
        for (int nt = 0; nt < 4; nt++) {
          float p = fast_exp2(sb[nt][r]);
          lpb[r] += p;
          pldsb[wv][(quad * 4 + r) * LSTR + nt * 16 + l15] = (__bf16)p;
        }
    }
    // softmax half a (only on dual tiles; masked at s==qb0)
    if (dual) {
      if (s == qb0) {
#pragma unroll
        for (int r = 0; r < 4; r++) {
          const int qloc = wv * 16 + quad * 4 + r;
#pragma unroll
          for (int nt = 0; nt < 4; nt++) {
            int kloc = nt * 16 + l15;
            float p = (kloc <= qloc) ? fast_exp2(sa[nt][r]) : 0.f;
            lpa[r] += p;
            pldsa[wv][(quad * 4 + r) * LSTR + nt * 16 + l15] = (__bf16)p;
          }
        }
      } else {
#pragma unroll
        for (int r = 0; r < 4; r++)
#pragma unroll
          for (int nt = 0; nt < 4; nt++) {
            float p = fast_exp2(sa[nt][r]);
            lpa[r] += p;
            pldsa[wv][(quad * 4 + r) * LSTR + nt * 16 + l15] = (__bf16)p;
          }
      }
    }

    // PV: shared V-frags feed both halves
    if (dual) {
#pragma unroll
      for (int kb = 0; kb < 2; kb++) {
        bf16x8 apb = *(const bf16x8*)(&pldsb[wv][l15 * LSTR + kb * 32 + quad * 8]);
        bf16x8 apa = *(const bf16x8*)(&pldsa[wv][l15 * LSTR + kb * 32 + quad * 8]);
#pragma unroll
        for (int dt = 0; dt < 4; dt++) {
          bf16x8 bvv = *(const bf16x8*)(vb_ + (dt * 16 + l15) * LSTR + kb * 32 + quad * 8);
          accb[dt] = __builtin_amdgcn_mfma_f32_16x16x32_bf16(apb, bvv, accb[dt], 0, 0, 0);
          acca[dt] = __builtin_amdgcn_mfma_f32_16x16x32_bf16(apa, bvv, acca[dt], 0, 0, 0);
        }
      }
    } else {
#pragma unroll
      for (int kb = 0; kb < 2; kb++) {
        bf16x8 apb = *(const bf16x8*)(&pldsb[wv][l15 * LSTR + kb * 32 + quad * 8]);
#pragma unroll
        for (int dt = 0; dt < 4; dt++) {
          bf16x8 bvv = *(const bf16x8*)(vb_ + (dt * 16 + l15) * LSTR + kb * 32 + quad * 8);
          accb[dt] = __builtin_amdgcn_mfma_f32_16x16x32_bf16(apb, bvv, accb[dt], 0, 0, 0);
        }
      }
    }

    if (s + 1 <= qb1) store_tile(cur ^ 1);
    __syncthreads();
    if (s == qb0) finalize(lpa, acca, qr0a);
  }
  finalize(lpb, accb, qr0b);
}

// ---------------- output projection + bias (fp32 out) ----------------
__global__ __launch_bounds__(256) void k_gemm_out(const __bf16* __restrict__ ctx,
    const __bf16* __restrict__ wot, const float* __restrict__ bo,
    float* __restrict__ out) {
  __shared__ __bf16 At[128 * 32];
  __shared__ __bf16 Bl[128 * 32];
  const int bm = blockIdx.y * 128, bn = blockIdx.x * 128;
  f32x4 acc[4][4];
  const f32x4 z = {0.f, 0.f, 0.f, 0.f};
#pragma unroll
  for (int mt = 0; mt < 4; mt++)
#pragma unroll
    for (int nt = 0; nt < 4; nt++) acc[mt][nt] = z;
  gemm_mainloop(ctx, wot, bm, bn, At, Bl, acc);
  const int lane = threadIdx.x & 63;
  const int l15 = lane & 15, quad = lane >> 4;
  const int wv = threadIdx.x >> 6;
  const int wm = (wv >> 1) * 64, wn = (wv & 1) * 64;
#pragma unroll
  for (int mt = 0; mt < 4; mt++)
#pragma unroll
    for (int nt = 0; nt < 4; nt++)
#pragma unroll
      for (int r = 0; r < 4; r++) {
        int m = bm + wm + mt * 16 + quad * 4 + r;
        int n = bn + wn + nt * 16 + l15;
        out[(size_t)m * DMODEL + n] = acc[mt][nt][r] + bo[n];
      }
}

extern "C" void kernel_launch(void* const* d_in, const int* in_sizes, int n_in,
                              void* d_out, int out_size, void* d_ws, size_t ws_size,
                              hipStream_t stream) {
  const float* x  = (const float*)d_in[0];
  const float* Wq = (const float*)d_in[1];
  const float* Wk = (const float*)d_in[2];
  const float* Wv = (const float*)d_in[3];
  const float* Wo = (const float*)d_in[4];
  const float* bo = (const float*)d_in[5];
  float* out = (float*)d_out;

  __bf16* xbf  = (__bf16*)d_ws;                       // 4096*1024
  __bf16* wt   = xbf  + (size_t)4096 * 1024;          // 4 * 1024*1024
  __bf16* qws  = wt   + (size_t)4 * 1024 * 1024;      // [32][2048][64]
  __bf16* kws  = qws  + (size_t)32 * 2048 * 64;
  __bf16* vtws = kws  + (size_t)32 * 2048 * 64;       // [32][64][VSTRIDE]
  __bf16* ctx  = xbf;                                 // aliases xbf (dead after QKV)

  k_prep<<<8192, 256, 0, stream>>>(x, Wq, Wk, Wv, Wo, xbf, wt);
  k_gemm_qkv<<<dim3(8, 32, 3), 256, 0, stream>>>(xbf, wt, qws, kws, vtws);
  k_attn<<<512, 256, 0, stream>>>(qws, kws, vtws, ctx);
  k_gemm_out<<<dim3(8, 32), 256, 0, stream>>>(ctx, wt + (size_t)3 * 1024 * 1024, bo, out);
}